// Round 8
// baseline (359.010 us; speedup 1.0000x reference)
//
#include <hip/hip_runtime.h>

// (B, D, T, V) = (16, 128, 4096, 1024)
#define B_ 16
#define D_ 128
#define T_ 4096
#define V_ 1024

typedef _Float16 half8 __attribute__((ext_vector_type(8)));
typedef float float4v __attribute__((ext_vector_type(4)));

// ws layout:
//   [0,       4096)   : chsq (V floats) = 0.5*|c|^2
//   [4096,  266240)   : Bh   (4 kt x 1024 v x 32 kk) f16 hi split
//   [266240,528384)   : Bl   (same, lo split scaled by 2048)
//
// LESSONS (counter-backed):
//  R9:  bank conflicts 4.3M->131K -> null. R10: occ 19->37% -> null.
//  R11: fused intervals -> 90us. R12: private-B -> 91us. R13: acc-split
//  -> 90us. R14: 4 blocks/CU (64-t tiles) -> 85us. Serial-sum model fits:
//  ~1866 matrix + ~1800 LDS + ~1280 VALU ~= 5145 cyc/chunk measured.
//  R15 (this): SACRIFICIAL ABLATION ROUND. Four probe dispatches (R3 body,
//  one phase stubbed each, DCE-pinned), then the verbatim-R3 real kernel
//  overwrites out -> absmax stays 0. dur_us inflated ~5x on purpose; the
//  per-dispatch rocprof rows give the marginal cost of each phase.

// Fused: split codebook into f16 hi/lo fragments AND compute chsq.
__global__ __launch_bounds__(256) void split_csq_kernel(const float* __restrict__ cb,
                                                        _Float16* __restrict__ Bh,
                                                        _Float16* __restrict__ Bl,
                                                        float* __restrict__ chsq) {
    const int g = blockIdx.x * 256 + threadIdx.x;  // 16384 threads
    const int v = g >> 4;
    const int k0 = (g & 15) << 3;
    const float* src = cb + (size_t)v * D_ + k0;
    half8 h, l;
    float s = 0.f;
#pragma unroll
    for (int j = 0; j < 8; ++j) {
        float c = src[j];
        _Float16 ch = (_Float16)c;
        h[j] = ch;
        l[j] = (_Float16)((c - (float)ch) * 2048.0f);
        s = fmaf(c, c, s);
    }
    const int kt = k0 >> 5;
    const int kk = k0 & 31;
    const size_t off = ((size_t)(kt * V_ + v)) * 32 + kk;
    *(half8*)(Bh + off) = h;
    *(half8*)(Bl + off) = l;
#pragma unroll
    for (int o = 1; o < 16; o <<= 1) s += __shfl_xor(s, o, 64);
    if ((g & 15) == 0) chsq[v] = 0.5f * s;
}

// Async 16B/lane global->LDS copy (wave-uniform LDS base, lane i -> +i*16).
__device__ __forceinline__ void dma16(const char* g, char* lds) {
    __builtin_amdgcn_global_load_lds(
        (const __attribute__((address_space(1))) unsigned int*)g,
        (__attribute__((address_space(3))) unsigned int*)lds, 16, 0, 0);
}

// Stage one 32-v chunk (16 KB) into ldsbuf; 8 waves x 2 segs. swoff
// pre-applies the bank swizzle on the GLOBAL source (LDS dest linear,
// rule 21); read side applies the same XOR (conflict-free, verified R9).
__device__ __forceinline__ void dma_chunk(char* ldsbuf, const char* BhB, const char* BlB,
                                          int c, int wv, int swoff) {
#pragma unroll
    for (int j = 0; j < 2; ++j) {
        const int seg = wv * 2 + j;
        const int hl = seg >> 3;
        const int kt = (seg >> 1) & 3;
        const char* src = (hl ? BlB : BhB) + kt * 65536 + c * 2048 + j * 1024 + swoff;
        dma16(src, ldsbuf + seg * 1024);
    }
}

// ---- PROBE: R3 body with one phase stubbed (MODE bit0=noMFMA, bit1=noLDSread,
// bit2=noFOLD, bit3=noDMA). Writes garbage to out; real kernel overwrites.
template <int MODE>
__global__ __launch_bounds__(512) void vq_probe(const float* __restrict__ latents,
                                                const float* __restrict__ codebook,
                                                const float* __restrict__ chsq,
                                                const _Float16* __restrict__ Bh,
                                                const _Float16* __restrict__ Bl,
                                                float* __restrict__ out_codes,
                                                float* __restrict__ out_q) {
    __shared__ __align__(16) char smem[69632];
    __shared__ float sChsq[V_];
    __shared__ int scode[128];
    __shared__ float sBestF[2][128];
    __shared__ int sBestV[2][128];

    const int tid = threadIdx.x;
    const int tl = tid & 63;
    const int wv = tid >> 6;
    const int wt = wv & 3;
    const int wn = wv >> 2;
    const int ln = tid & 15;
    const int q = (tid >> 4) & 3;
    const int b = blockIdx.x >> 5;
    const int t00 = (blockIdx.x & 31) << 7;

    const int swoff = ((tl >> 2) << 6) + ((((tl & 3) ^ ((tl >> 3) & 3))) << 4);
    const int qs16 = ((q ^ ((ln >> 1) & 3)) << 4);

    _Float16* AhS = (_Float16*)smem;
    _Float16* AlS = AhS + 128 * 136;

#pragma unroll
    for (int i = 0; i < V_ / 512; ++i) sChsq[tid + i * 512] = chsq[tid + i * 512];

    {
        const int arow = tid & 127;
        const int adh = tid >> 7;
        const float* xp = latents + (size_t)b * D_ * T_ + t00 + arow;
#pragma unroll
        for (int i = 0; i < 4; ++i) {
            const int d0 = adh * 32 + i * 8;
            float x[8];
#pragma unroll
            for (int j = 0; j < 8; ++j) x[j] = xp[(size_t)(d0 + j) * T_];
            half8 h, l;
#pragma unroll
            for (int j = 0; j < 8; ++j) {
                _Float16 xh = (_Float16)x[j];
                h[j] = xh;
                l[j] = (_Float16)((x[j] - (float)xh) * 2048.0f);
            }
            *(half8*)(AhS + arow * 136 + d0) = h;
            *(half8*)(AlS + arow * 136 + d0) = l;
        }
    }
    __syncthreads();

    half8 ah[4][2], al[4][2];
#pragma unroll
    for (int kt = 0; kt < 4; ++kt)
#pragma unroll
        for (int mt = 0; mt < 2; ++mt) {
            const int row = wt * 32 + mt * 16 + ln;
            ah[kt][mt] = *(const half8*)(AhS + row * 136 + kt * 32 + q * 8);
            al[kt][mt] = *(const half8*)(AlS + row * 136 + kt * 32 + q * 8);
        }
    __syncthreads();

    char* Bb = smem;
    const char* BhB = (const char*)Bh;
    const char* BlB = (const char*)Bl;

    // opaque zero: compiler cannot constant-fold stubbed-phase inputs (rule 17)
    float z0;
    asm volatile("v_mov_b32 %0, 0" : "=v"(z0));

    float bestF[2][4];
    int bestv[2][4];
#pragma unroll
    for (int mt = 0; mt < 2; ++mt)
#pragma unroll
        for (int r = 0; r < 4; ++r) {
            bestF[mt][r] = 3.0e38f;
            bestv[mt][r] = 0;
        }

    if constexpr (!(MODE & 8)) {
        dma_chunk(Bb + 0 * 16384, BhB, BlB, 0, wv, swoff);
        dma_chunk(Bb + 1 * 16384, BhB, BlB, 1, wv, swoff);
        dma_chunk(Bb + 2 * 16384, BhB, BlB, 2, wv, swoff);
    }

    for (int c = 0; c < 32; ++c) {
        if constexpr (!(MODE & 8)) {
            asm volatile("s_waitcnt vmcnt(4)" ::: "memory");
        }
        __builtin_amdgcn_s_barrier();
        asm volatile("" ::: "memory");

        if constexpr (!(MODE & 8)) {
            dma_chunk(Bb + ((c + 3) & 3) * 16384, BhB, BlB, (c + 3) & 31, wv, swoff);
        }

        const char* buf = Bb + (c & 3) * 16384;
        float4v acc1[2], acc2[2];
#pragma unroll
        for (int mt = 0; mt < 2; ++mt) {
            acc1[mt] = (float4v){z0, z0, z0, z0};
            acc2[mt] = (float4v){z0, z0, z0, z0};
        }
        __builtin_amdgcn_s_setprio(1);
#pragma unroll
        for (int kt = 0; kt < 4; ++kt) {
            half8 bh, bl;
            if constexpr (!(MODE & 2)) {
                const int o = kt * 2048 + (wn * 16 + ln) * 64 + qs16;
                bh = *(const half8*)(buf + o);
                bl = *(const half8*)(buf + 8192 + o);
            } else {
                bh = ah[kt][0];  // register-sourced garbage (keeps MFMA count)
                bl = al[kt][0];
            }
            if constexpr (!(MODE & 1)) {
#pragma unroll
                for (int mt = 0; mt < 2; ++mt) {
                    acc1[mt] = __builtin_amdgcn_mfma_f32_16x16x32_f16(ah[kt][mt], bh,
                                                                      acc1[mt], 0, 0, 0);
                    acc2[mt] = __builtin_amdgcn_mfma_f32_16x16x32_f16(ah[kt][mt], bl,
                                                                      acc2[mt], 0, 0, 0);
                    acc2[mt] = __builtin_amdgcn_mfma_f32_16x16x32_f16(al[kt][mt], bh,
                                                                      acc2[mt], 0, 0, 0);
                }
            } else {
                // pin loaded B-frags live so ds_reads aren't DCE'd
                float4v pb = __builtin_bit_cast(float4v, bh);
                float4v pl = __builtin_bit_cast(float4v, bl);
                asm volatile("" ::"v"(pb[0]), "v"(pb[1]), "v"(pb[2]), "v"(pb[3]),
                             "v"(pl[0]), "v"(pl[1]), "v"(pl[2]), "v"(pl[3]));
            }
        }
        __builtin_amdgcn_s_setprio(0);
        if constexpr (!(MODE & 4)) {
            const int n = c * 32 + wn * 16 + ln;
            const float csq = sChsq[n];
#pragma unroll
            for (int mt = 0; mt < 2; ++mt)
#pragma unroll
                for (int r = 0; r < 4; ++r) {
                    const float score =
                        csq - (acc1[mt][r] + acc2[mt][r] * (1.0f / 2048.0f));
                    if (score < bestF[mt][r]) {
                        bestF[mt][r] = score;
                        bestv[mt][r] = n;
                    }
                }
        } else {
            // pin accs live so MFMAs aren't DCE'd
#pragma unroll
            for (int mt = 0; mt < 2; ++mt) {
                asm volatile("" ::"v"(acc1[mt][0]), "v"(acc1[mt][1]), "v"(acc1[mt][2]),
                             "v"(acc1[mt][3]), "v"(acc2[mt][0]), "v"(acc2[mt][1]),
                             "v"(acc2[mt][2]), "v"(acc2[mt][3]));
            }
        }
    }

#pragma unroll
    for (int off = 1; off < 16; off <<= 1) {
#pragma unroll
        for (int mt = 0; mt < 2; ++mt)
#pragma unroll
            for (int r = 0; r < 4; ++r) {
                const float of = __shfl_xor(bestF[mt][r], off, 64);
                const int ov = __shfl_xor(bestv[mt][r], off, 64);
                if (of < bestF[mt][r] || (of == bestF[mt][r] && ov < bestv[mt][r])) {
                    bestF[mt][r] = of;
                    bestv[mt][r] = ov;
                }
            }
    }
    if (ln == 0) {
#pragma unroll
        for (int mt = 0; mt < 2; ++mt)
#pragma unroll
            for (int r = 0; r < 4; ++r) {
                const int m = wt * 32 + mt * 16 + q * 4 + r;
                sBestF[wn][m] = bestF[mt][r];
                sBestV[wn][m] = bestv[mt][r];
            }
    }
    __syncthreads();
    if (tid < 128) {
        const float f0 = sBestF[0][tid];
        const float f1 = sBestF[1][tid];
        const int v0 = sBestV[0][tid];
        const int v1 = sBestV[1][tid];
        const int vb = (f1 < f0 || (f1 == f0 && v1 < v0)) ? v1 : v0;
        scode[tid] = vb;
        out_codes[(size_t)b * T_ + t00 + tid] = (float)vb;
    }
    __syncthreads();
    {
        const int row = tid & 127;
        const int dq = tid >> 7;
        const int code = scode[row];
        const float* crow = codebook + (size_t)code * D_;
        float* qp = out_q + (size_t)b * D_ * T_ + t00 + row;
#pragma unroll
        for (int i = 0; i < 32; ++i) {
            const int d = dq * 32 + i;
            qp[(size_t)d * T_] = crow[d];
        }
    }
}

// ---- REAL kernel: verbatim R3 (best known, 68.6us, absmax 0) ----
__global__ __launch_bounds__(512) void vq_mfma(const float* __restrict__ latents,
                                               const float* __restrict__ codebook,
                                               const float* __restrict__ chsq,
                                               const _Float16* __restrict__ Bh,
                                               const _Float16* __restrict__ Bl,
                                               float* __restrict__ out_codes,
                                               float* __restrict__ out_q) {
    __shared__ __align__(16) char smem[69632];
    __shared__ float sChsq[V_];
    __shared__ int scode[128];
    __shared__ float sBestF[2][128];
    __shared__ int sBestV[2][128];

    const int tid = threadIdx.x;
    const int tl = tid & 63;
    const int wv = tid >> 6;
    const int wt = wv & 3;
    const int wn = wv >> 2;
    const int ln = tid & 15;
    const int q = (tid >> 4) & 3;
    const int b = blockIdx.x >> 5;
    const int t00 = (blockIdx.x & 31) << 7;

    const int swoff = ((tl >> 2) << 6) + ((((tl & 3) ^ ((tl >> 3) & 3))) << 4);
    const int qs16 = ((q ^ ((ln >> 1) & 3)) << 4);

    _Float16* AhS = (_Float16*)smem;
    _Float16* AlS = AhS + 128 * 136;

#pragma unroll
    for (int i = 0; i < V_ / 512; ++i) sChsq[tid + i * 512] = chsq[tid + i * 512];

    {
        const int arow = tid & 127;
        const int adh = tid >> 7;
        const float* xp = latents + (size_t)b * D_ * T_ + t00 + arow;
#pragma unroll
        for (int i = 0; i < 4; ++i) {
            const int d0 = adh * 32 + i * 8;
            float x[8];
#pragma unroll
            for (int j = 0; j < 8; ++j) x[j] = xp[(size_t)(d0 + j) * T_];
            half8 h, l;
#pragma unroll
            for (int j = 0; j < 8; ++j) {
                _Float16 xh = (_Float16)x[j];
                h[j] = xh;
                l[j] = (_Float16)((x[j] - (float)xh) * 2048.0f);
            }
            *(half8*)(AhS + arow * 136 + d0) = h;
            *(half8*)(AlS + arow * 136 + d0) = l;
        }
    }
    __syncthreads();

    half8 ah[4][2], al[4][2];
#pragma unroll
    for (int kt = 0; kt < 4; ++kt)
#pragma unroll
        for (int mt = 0; mt < 2; ++mt) {
            const int row = wt * 32 + mt * 16 + ln;
            ah[kt][mt] = *(const half8*)(AhS + row * 136 + kt * 32 + q * 8);
            al[kt][mt] = *(const half8*)(AlS + row * 136 + kt * 32 + q * 8);
        }
    __syncthreads();

    char* Bb = smem;
    const char* BhB = (const char*)Bh;
    const char* BlB = (const char*)Bl;

    float bestF[2][4];
    int bestv[2][4];
#pragma unroll
    for (int mt = 0; mt < 2; ++mt)
#pragma unroll
        for (int r = 0; r < 4; ++r) {
            bestF[mt][r] = 3.0e38f;
            bestv[mt][r] = 0;
        }

    dma_chunk(Bb + 0 * 16384, BhB, BlB, 0, wv, swoff);
    dma_chunk(Bb + 1 * 16384, BhB, BlB, 1, wv, swoff);
    dma_chunk(Bb + 2 * 16384, BhB, BlB, 2, wv, swoff);

    for (int c = 0; c < 32; ++c) {
        asm volatile("s_waitcnt vmcnt(4)" ::: "memory");
        __builtin_amdgcn_s_barrier();
        asm volatile("" ::: "memory");

        dma_chunk(Bb + ((c + 3) & 3) * 16384, BhB, BlB, (c + 3) & 31, wv, swoff);

        const char* buf = Bb + (c & 3) * 16384;
        float4v acc1[2], acc2[2];
#pragma unroll
        for (int mt = 0; mt < 2; ++mt) {
            acc1[mt] = (float4v){0.f, 0.f, 0.f, 0.f};
            acc2[mt] = (float4v){0.f, 0.f, 0.f, 0.f};
        }
        __builtin_amdgcn_s_setprio(1);
#pragma unroll
        for (int kt = 0; kt < 4; ++kt) {
            const int o = kt * 2048 + (wn * 16 + ln) * 64 + qs16;
            const half8 bh = *(const half8*)(buf + o);
            const half8 bl = *(const half8*)(buf + 8192 + o);
#pragma unroll
            for (int mt = 0; mt < 2; ++mt) {
                acc1[mt] = __builtin_amdgcn_mfma_f32_16x16x32_f16(ah[kt][mt], bh,
                                                                  acc1[mt], 0, 0, 0);
                acc2[mt] = __builtin_amdgcn_mfma_f32_16x16x32_f16(ah[kt][mt], bl,
                                                                  acc2[mt], 0, 0, 0);
                acc2[mt] = __builtin_amdgcn_mfma_f32_16x16x32_f16(al[kt][mt], bh,
                                                                  acc2[mt], 0, 0, 0);
            }
        }
        __builtin_amdgcn_s_setprio(0);
        {
            const int n = c * 32 + wn * 16 + ln;
            const float csq = sChsq[n];
#pragma unroll
            for (int mt = 0; mt < 2; ++mt)
#pragma unroll
                for (int r = 0; r < 4; ++r) {
                    const float score =
                        csq - (acc1[mt][r] + acc2[mt][r] * (1.0f / 2048.0f));
                    if (score < bestF[mt][r]) {
                        bestF[mt][r] = score;
                        bestv[mt][r] = n;
                    }
                }
        }
    }

#pragma unroll
    for (int off = 1; off < 16; off <<= 1) {
#pragma unroll
        for (int mt = 0; mt < 2; ++mt)
#pragma unroll
            for (int r = 0; r < 4; ++r) {
                const float of = __shfl_xor(bestF[mt][r], off, 64);
                const int ov = __shfl_xor(bestv[mt][r], off, 64);
                if (of < bestF[mt][r] || (of == bestF[mt][r] && ov < bestv[mt][r])) {
                    bestF[mt][r] = of;
                    bestv[mt][r] = ov;
                }
            }
    }

    if (ln == 0) {
#pragma unroll
        for (int mt = 0; mt < 2; ++mt)
#pragma unroll
            for (int r = 0; r < 4; ++r) {
                const int m = wt * 32 + mt * 16 + q * 4 + r;
                sBestF[wn][m] = bestF[mt][r];
                sBestV[wn][m] = bestv[mt][r];
            }
    }
    __syncthreads();

    if (tid < 128) {
        const float f0 = sBestF[0][tid];
        const float f1 = sBestF[1][tid];
        const int v0 = sBestV[0][tid];
        const int v1 = sBestV[1][tid];
        const int vb = (f1 < f0 || (f1 == f0 && v1 < v0)) ? v1 : v0;
        scode[tid] = vb;
        out_codes[(size_t)b * T_ + t00 + tid] = (float)vb;
    }
    __syncthreads();

    {
        const int row = tid & 127;
        const int dq = tid >> 7;
        const int code = scode[row];
        const float* crow = codebook + (size_t)code * D_;
        float* qp = out_q + (size_t)b * D_ * T_ + t00 + row;
#pragma unroll
        for (int i = 0; i < 32; ++i) {
            const int d = dq * 32 + i;
            qp[(size_t)d * T_] = crow[d];
        }
    }
}

extern "C" void kernel_launch(void* const* d_in, const int* in_sizes, int n_in,
                              void* d_out, int out_size, void* d_ws, size_t ws_size,
                              hipStream_t stream) {
    const float* latents = (const float*)d_in[0];   // (B, D, T) f32
    const float* codebook = (const float*)d_in[1];  // (V, D) f32

    float* out_codes = (float*)d_out;        // (B, T) codes as f32 values
    float* out_q = (float*)d_out + B_ * T_;  // (B, D, T) quantized f32

    float* chsq = (float*)d_ws;
    _Float16* Bh = (_Float16*)((char*)d_ws + 4096);
    _Float16* Bl = (_Float16*)((char*)d_ws + 4096 + 262144);

    split_csq_kernel<<<(V_ * 16) / 256, 256, 0, stream>>>(codebook, Bh, Bl, chsq);

    // diagnostic probes (write garbage to out; real kernel below overwrites)
    vq_probe<1><<<(B_ * T_) / 128, 512, 0, stream>>>(latents, codebook, chsq, Bh, Bl,
                                                     out_codes, out_q);  // noMFMA
    vq_probe<2><<<(B_ * T_) / 128, 512, 0, stream>>>(latents, codebook, chsq, Bh, Bl,
                                                     out_codes, out_q);  // noLDSread
    vq_probe<4><<<(B_ * T_) / 128, 512, 0, stream>>>(latents, codebook, chsq, Bh, Bl,
                                                     out_codes, out_q);  // noFOLD
    vq_probe<8><<<(B_ * T_) / 128, 512, 0, stream>>>(latents, codebook, chsq, Bh, Bl,
                                                     out_codes, out_q);  // noDMA

    // real kernel (verbatim R3) -- produces the graded output
    vq_mfma<<<(B_ * T_) / 128, 512, 0, stream>>>(latents, codebook, chsq, Bh, Bl,
                                                 out_codes, out_q);
}

// Round 9
// 132.143 us; speedup vs baseline: 2.7168x; 2.7168x over previous
//
#include <hip/hip_runtime.h>

// (B, D, T, V) = (16, 128, 4096, 1024)
#define B_ 16
#define D_ 128
#define T_ 4096
#define V_ 1024

typedef _Float16 half8 __attribute__((ext_vector_type(8)));
typedef float float4v __attribute__((ext_vector_type(4)));

// ws layout:
//   [0,       4096)   : chsq (V floats) = 0.5*|c|^2
//   [4096,  266240)   : Bh   (4 kt x 1024 v x 32 kk) f16 hi split
//   [266240,528384)   : Bl   (same, lo split scaled by 2048)
//
// LESSONS (counter-backed):
//  R9:  bank conflicts 4.3M->131K -> null.  R10: occupancy 2x -> null.
//  R11-R14: coarse re-phasing / private-B / acc-split / 4-blocks -> 85-92us.
//  R15: probe round inconclusive (top-5 truncation); BUT rule-19 verified:
//    source-identical R3 co-compiled w/ probes: VGPR 64->72, 68.6->84.7us.
//    Combined w/ R13 (+12 VGPR -> 90us): 512-thr VGPR>64 = cliff to ~85-91.
//    256-thr tolerates VGPR 88 (R1/R2 = 67-68.6).
//  => Model: matrix 1862 + LDS 1540 + VALU 1290 cyc/chunk/CU ~= 5150 wall:
//     pipes SERIALIZE (m97-class 36% signature). Cure per m196/m233: fine
//     ds_read||MFMA interleave across the sync boundary, at 256-thr.
//  R16 (this): cross-chunk one-kt-ahead B-frag register pipeline. vmcnt(4)
//     tightened to retire chunks c AND c+1 -> next chunk's LDS readable
//     during current chunk; loads run 1 kt ahead continuously across the
//     barrier. Sync at loop bottom. Numerics order per-acc unchanged.

// Fused: split codebook into f16 hi/lo fragments AND compute chsq.
__global__ __launch_bounds__(256) void split_csq_kernel(const float* __restrict__ cb,
                                                        _Float16* __restrict__ Bh,
                                                        _Float16* __restrict__ Bl,
                                                        float* __restrict__ chsq) {
    const int g = blockIdx.x * 256 + threadIdx.x;  // 16384 threads
    const int v = g >> 4;
    const int k0 = (g & 15) << 3;
    const float* src = cb + (size_t)v * D_ + k0;
    half8 h, l;
    float s = 0.f;
#pragma unroll
    for (int j = 0; j < 8; ++j) {
        float c = src[j];
        _Float16 ch = (_Float16)c;
        h[j] = ch;
        l[j] = (_Float16)((c - (float)ch) * 2048.0f);
        s = fmaf(c, c, s);
    }
    const int kt = k0 >> 5;
    const int kk = k0 & 31;
    const size_t off = ((size_t)(kt * V_ + v)) * 32 + kk;
    *(half8*)(Bh + off) = h;
    *(half8*)(Bl + off) = l;
#pragma unroll
    for (int o = 1; o < 16; o <<= 1) s += __shfl_xor(s, o, 64);
    if ((g & 15) == 0) chsq[v] = 0.5f * s;
}

// Async 16B/lane global->LDS copy (wave-uniform LDS base, lane i -> +i*16).
__device__ __forceinline__ void dma16(const char* g, char* lds) {
    __builtin_amdgcn_global_load_lds(
        (const __attribute__((address_space(1))) unsigned int*)g,
        (__attribute__((address_space(3))) unsigned int*)lds, 16, 0, 0);
}

// Stage one 32-v chunk (16 KB: Bh 8KB + Bl 8KB) into ldsbuf; 4 waves x 4 segs.
// seg = wq*4+j in [0,16): bits [3]=h/l, [2:1]=kt, [0]=which 1KB of 2KB slice.
// swoff pre-applies the bank swizzle on the GLOBAL source (LDS dest linear,
// rule 21): LDS unit (v, q') holds global (v, q'^s(v)), s(v)=(v>>1)&3.
// Read side applies the same XOR -> conflict-free b128 reads (verified R9).
__device__ __forceinline__ void dma_chunk(char* ldsbuf, const char* BhB, const char* BlB,
                                          int c, int wq, int swoff) {
#pragma unroll
    for (int j = 0; j < 4; ++j) {
        const int seg = wq * 4 + j;
        const int hl = seg >> 3;
        const int kt = (seg >> 1) & 3;
        const int o1k = seg & 1;
        const char* src = (hl ? BlB : BhB) + kt * 65536 + c * 2048 + o1k * 1024 + swoff;
        dma16(src, ldsbuf + seg * 1024);
    }
}

struct Frag {
    half8 bh0, bh1, bl0, bl1;
};

__device__ __forceinline__ Frag ldfrag(const char* buf, int kt, int o0, int o1) {
    Frag f;
    f.bh0 = *(const half8*)(buf + kt * 2048 + o0);
    f.bh1 = *(const half8*)(buf + kt * 2048 + o1);
    f.bl0 = *(const half8*)(buf + 8192 + kt * 2048 + o0);
    f.bl1 = *(const half8*)(buf + 8192 + kt * 2048 + o1);
    return f;
}

// 12 MFMAs for one kt-step. Per-accumulator accumulation order identical to
// the proven R2 kernel (kt ascending; acc2: ah*bl then al*bh) -> absmax 0.
#define MSTEP(f, kt)                                                                   \
    {                                                                                  \
        _Pragma("unroll") for (int mt = 0; mt < 2; ++mt) {                             \
            acc1[mt][0] = __builtin_amdgcn_mfma_f32_16x16x32_f16(ah[kt][mt], (f).bh0,  \
                                                                 acc1[mt][0], 0, 0, 0); \
            acc1[mt][1] = __builtin_amdgcn_mfma_f32_16x16x32_f16(ah[kt][mt], (f).bh1,  \
                                                                 acc1[mt][1], 0, 0, 0); \
            acc2[mt][0] = __builtin_amdgcn_mfma_f32_16x16x32_f16(ah[kt][mt], (f).bl0,  \
                                                                 acc2[mt][0], 0, 0, 0); \
            acc2[mt][1] = __builtin_amdgcn_mfma_f32_16x16x32_f16(ah[kt][mt], (f).bl1,  \
                                                                 acc2[mt][1], 0, 0, 0); \
            acc2[mt][0] = __builtin_amdgcn_mfma_f32_16x16x32_f16(al[kt][mt], (f).bh0,  \
                                                                 acc2[mt][0], 0, 0, 0); \
            acc2[mt][1] = __builtin_amdgcn_mfma_f32_16x16x32_f16(al[kt][mt], (f).bh1,  \
                                                                 acc2[mt][1], 0, 0, 0); \
        }                                                                              \
    }

// Main kernel: block = 256 thr = 4 waves; tile = 128 t x all 1024 v; grid 512
// = 2 blocks/CU. Wave wq owns t-rows [wq*32,+32) (mt=2), sweeps ALL v (ntl=2).
// B from 4-slot LDS ring; B-frag ds_reads pipelined ONE kt-step ahead in
// registers, continuing across the chunk boundary (next chunk's slot is
// data-valid: bottom vmcnt(4) retires chunks c+1 AND c+2). One raw s_barrier
// per chunk at loop bottom. Dual accumulators (absmax 0 proven):
//   acc1 = sum_k xh*ch ; acc2 = sum_k (xh*cl' + xl'*ch)   (lo pre-scaled 2048)
//   score = 0.5|c|^2 - (acc1 + acc2/2048); running argmin, ties -> lowest v.
__global__ __launch_bounds__(256) void vq_mfma(const float* __restrict__ latents,
                                               const float* __restrict__ codebook,
                                               const float* __restrict__ chsq,
                                               const _Float16* __restrict__ Bh,
                                               const _Float16* __restrict__ Bl,
                                               float* __restrict__ out_codes,
                                               float* __restrict__ out_q) {
    // union: A-stage (128x136 x2 halves = 69632 B) then B 4-ring (4x16384)
    __shared__ __align__(16) char smem[69632];
    __shared__ float sChsq[V_];
    __shared__ int scode[128];

    const int tid = threadIdx.x;
    const int tl = tid & 63;
    const int wq = tid >> 6;       // 0..3
    const int ln = tid & 15;       // MFMA col (n) / A row (m)
    const int q = (tid >> 4) & 3;  // quad
    const int b = blockIdx.x >> 5;           // 32 t-tiles of 128 per batch entry
    const int t00 = (blockIdx.x & 31) << 7;  // t-tile start

    const int swoff = ((tl >> 2) << 6) + ((((tl & 3) ^ ((tl >> 3) & 3))) << 4);
    const int qs16 = ((q ^ ((ln >> 1) & 3)) << 4);
    const int o0 = ln * 64 + qs16;         // ntl=0 fragment byte offset
    const int o1 = (16 + ln) * 64 + qs16;  // ntl=1

    _Float16* AhS = (_Float16*)smem;  // [128][136] (+8 pad)
    _Float16* AlS = AhS + 128 * 136;

    // ---- stage chsq into LDS ----
#pragma unroll
    for (int i = 0; i < V_ / 256; ++i) sChsq[tid + i * 256] = chsq[tid + i * 256];

    // ---- stage A tile (128 t x 128 d), f16 split, [t][k] rows ----
#pragma unroll
    for (int th = 0; th < 2; ++th) {
        const int row = th * 64 + tl;
        const float* xp = latents + (size_t)b * D_ * T_ + t00 + row;
#pragma unroll
        for (int i = 0; i < 4; ++i) {
            const int d0 = wq * 32 + i * 8;
            float x[8];
#pragma unroll
            for (int j = 0; j < 8; ++j) x[j] = xp[(size_t)(d0 + j) * T_];
            half8 h, l;
#pragma unroll
            for (int j = 0; j < 8; ++j) {
                _Float16 xh = (_Float16)x[j];
                h[j] = xh;
                l[j] = (_Float16)((x[j] - (float)xh) * 2048.0f);
            }
            *(half8*)(AhS + row * 136 + d0) = h;
            *(half8*)(AlS + row * 136 + d0) = l;
        }
    }
    __syncthreads();

    // ---- extract A fragments to registers: wave owns rows wq*32..+32 ----
    half8 ah[4][2], al[4][2];  // [kt][mt] : 64 VGPRs
#pragma unroll
    for (int kt = 0; kt < 4; ++kt)
#pragma unroll
        for (int mt = 0; mt < 2; ++mt) {
            const int row = wq * 32 + mt * 16 + ln;
            ah[kt][mt] = *(const half8*)(AhS + row * 136 + kt * 32 + q * 8);
            al[kt][mt] = *(const half8*)(AlS + row * 136 + kt * 32 + q * 8);
        }
    __syncthreads();  // A region dead -> reuse as B ring

    char* Bb = smem;  // [4][16384]
    const char* BhB = (const char*)Bh;
    const char* BlB = (const char*)Bl;

    float bestF[2][2][4];  // [mt][ntl][r]
    int bestv[2][2][4];
#pragma unroll
    for (int mt = 0; mt < 2; ++mt)
#pragma unroll
        for (int ntl = 0; ntl < 2; ++ntl)
#pragma unroll
            for (int r = 0; r < 4; ++r) {
                bestF[mt][ntl][r] = 3.0e38f;
                bestv[mt][ntl][r] = 0;
            }

    // ---- prologue: fill 3 ring slots (12 loads/wave in flight) ----
    dma_chunk(Bb + 0 * 16384, BhB, BlB, 0, wq, swoff);
    dma_chunk(Bb + 1 * 16384, BhB, BlB, 1, wq, swoff);
    dma_chunk(Bb + 2 * 16384, BhB, BlB, 2, wq, swoff);
    asm volatile("s_waitcnt vmcnt(4)" ::: "memory");  // own chunk-0,1 loads done
    __builtin_amdgcn_s_barrier();                     // -> block-wide: 0,1 ready
    asm volatile("" ::: "memory");

    Frag fcur = ldfrag(Bb, 0, o0, o1);  // chunk 0, kt 0

    for (int c = 0; c < 32; ++c) {
        const char* buf = Bb + (c & 3) * 16384;
        const char* bufn = Bb + ((c + 1) & 3) * 16384;
        // refill slot (c-1)&3 with chunk c+3 (readers done before the barrier
        // we just passed); tail wraps to dummy chunks (released slots, benign)
        dma_chunk(Bb + ((c + 3) & 3) * 16384, BhB, BlB, (c + 3) & 31, wq, swoff);

        float4v acc1[2][2], acc2[2][2];  // [mt][ntl]
#pragma unroll
        for (int mt = 0; mt < 2; ++mt)
#pragma unroll
            for (int ntl = 0; ntl < 2; ++ntl) {
                acc1[mt][ntl] = (float4v){0.f, 0.f, 0.f, 0.f};
                acc2[mt][ntl] = (float4v){0.f, 0.f, 0.f, 0.f};
            }

        __builtin_amdgcn_s_setprio(1);
        // one-kt-ahead pipeline; last stage preloads NEXT chunk's kt0 (its
        // data was guaranteed by the previous bottom vmcnt+barrier)
        Frag f1 = ldfrag(buf, 1, o0, o1);
        MSTEP(fcur, 0);
        Frag f2 = ldfrag(buf, 2, o0, o1);
        MSTEP(f1, 1);
        Frag f3 = ldfrag(buf, 3, o0, o1);
        MSTEP(f2, 2);
        Frag fnx = ldfrag(bufn, 0, o0, o1);
        MSTEP(f3, 3);
        __builtin_amdgcn_s_setprio(0);

        // fold scores into running argmin (ntl=0 first: lower v wins ties)
#pragma unroll
        for (int ntl = 0; ntl < 2; ++ntl) {
            const int n = c * 32 + ntl * 16 + ln;
            const float csq = sChsq[n];
#pragma unroll
            for (int mt = 0; mt < 2; ++mt)
#pragma unroll
                for (int r = 0; r < 4; ++r) {
                    const float score =
                        csq - (acc1[mt][ntl][r] + acc2[mt][ntl][r] * (1.0f / 2048.0f));
                    if (score < bestF[mt][ntl][r]) {  // strict < => lowest v on ties
                        bestF[mt][ntl][r] = score;
                        bestv[mt][ntl][r] = n;
                    }
                }
        }

        // bottom sync: retire chunks c+1 (next iter's f1-f3) and c+2 (its fnx);
        // barrier also releases slot (c)&3's readers for the next dma.
        asm volatile("s_waitcnt vmcnt(4)" ::: "memory");
        __builtin_amdgcn_s_barrier();
        asm volatile("" ::: "memory");
        fcur = fnx;
    }

    // merge ntl halves into one per-(mt,r) result (lex (f,v): lowest-v ties)
    float bF[2][4];
    int bV[2][4];
#pragma unroll
    for (int mt = 0; mt < 2; ++mt)
#pragma unroll
        for (int r = 0; r < 4; ++r) {
            const float f0 = bestF[mt][0][r], f1 = bestF[mt][1][r];
            const int v0 = bestv[mt][0][r], v1 = bestv[mt][1][r];
            const bool take1 = (f1 < f0) || (f1 == f0 && v1 < v0);
            bF[mt][r] = take1 ? f1 : f0;
            bV[mt][r] = take1 ? v1 : v0;
        }

    // cross-lane argmin over the 16-col group; ties -> lowest v
#pragma unroll
    for (int off = 1; off < 16; off <<= 1) {
#pragma unroll
        for (int mt = 0; mt < 2; ++mt)
#pragma unroll
            for (int r = 0; r < 4; ++r) {
                const float of = __shfl_xor(bF[mt][r], off, 64);
                const int ov = __shfl_xor(bV[mt][r], off, 64);
                if (of < bF[mt][r] || (of == bF[mt][r] && ov < bV[mt][r])) {
                    bF[mt][r] = of;
                    bV[mt][r] = ov;
                }
            }
    }

    // per-wave complete argmin: lanes ln==0 publish rows m = wq*32+mt*16+q*4+r
    if (ln == 0) {
#pragma unroll
        for (int mt = 0; mt < 2; ++mt)
#pragma unroll
            for (int r = 0; r < 4; ++r) {
                const int m = wq * 32 + mt * 16 + q * 4 + r;
                scode[m] = bV[mt][r];
                out_codes[(size_t)b * T_ + t00 + m] = (float)bV[mt][r];
            }
    }
    __syncthreads();  // also covers trailing dummy DMAs before LDS reuse ends

    // gather-write quantized[b, d, t00+row] = codebook[code, d]; coalesced
#pragma unroll
    for (int th = 0; th < 2; ++th) {
        const int row = th * 64 + tl;
        const int code = scode[row];
        const float* crow = codebook + (size_t)code * D_;
        float* qp = out_q + (size_t)b * D_ * T_ + t00 + row;
#pragma unroll
        for (int i = 0; i < 32; ++i) {
            const int d = wq * 32 + i;
            qp[(size_t)d * T_] = crow[d];
        }
    }
}

extern "C" void kernel_launch(void* const* d_in, const int* in_sizes, int n_in,
                              void* d_out, int out_size, void* d_ws, size_t ws_size,
                              hipStream_t stream) {
    const float* latents = (const float*)d_in[0];   // (B, D, T) f32
    const float* codebook = (const float*)d_in[1];  // (V, D) f32

    float* out_codes = (float*)d_out;        // (B, T) codes as f32 values
    float* out_q = (float*)d_out + B_ * T_;  // (B, D, T) quantized f32

    float* chsq = (float*)d_ws;
    _Float16* Bh = (_Float16*)((char*)d_ws + 4096);
    _Float16* Bl = (_Float16*)((char*)d_ws + 4096 + 262144);

    split_csq_kernel<<<(V_ * 16) / 256, 256, 0, stream>>>(codebook, Bh, Bl, chsq);
    vq_mfma<<<(B_ * T_) / 128, 256, 0, stream>>>(latents, codebook, chsq, Bh, Bl,
                                                 out_codes, out_q);
}